// Round 4
// baseline (123.575 us; speedup 1.0000x reference)
//
#include <hip/hip_runtime.h>

#define N_ATOMS 10000
#define N_EDGES 200000
#define ROW 44            // dwords per feature row (176 B, 16B-aligned)
#define W_F 0.6283185307179586f   // pi/5 in f32

// d_ws layout: feat[200000][44] floats at +0 (33.6 MiB); starts[10001] ints at +36 MiB.

// ---- kernel A: edge-parallel feature build + fused segment-starts search ----
__global__ __launch_bounds__(256) void edge_feat_kernel(
    const float* __restrict__ R,
    const int*   __restrict__ seg_i,
    const int*   __restrict__ idx_j,
    const int*   __restrict__ species,
    const float* __restrict__ emb,
    float*       __restrict__ feat,
    int*         __restrict__ starts)
{
    const int e = blockIdx.x * blockDim.x + threadIdx.x;

    if (e <= N_ATOMS) {           // starts[a] = lower_bound(seg_i, a)
        int lo = 0, hi = N_EDGES;
        while (lo < hi) {
            int mid = (lo + hi) >> 1;
            if (seg_i[mid] < e) lo = mid + 1; else hi = mid;
        }
        starts[e] = lo;
    }
    if (e >= N_EDGES) return;

    const int jj = idx_j[e];
    const float x = R[3*e + 0];
    const float y = R[3*e + 1];
    const float z = R[3*e + 2];
    const int sidx = species[jj];
    const float r   = sqrtf(x*x + y*y + z*z);
    const float inv = 1.0f / (r + 1e-12f);
    const float ux = x*inv, uy = y*inv, uz = z*inv;
    const float4 spv = *(const float4*)&emb[4 * sidx];

    // one sin + one cos; higher harmonics via Chebyshev recurrence
    const float t1 = W_F * r;
    const float s1 = sinf(t1);
    const float c1 = cosf(t1);
    const float fc = (r < 5.0f) ? (0.5f * (c1 + 1.0f)) : 0.0f;
    const float c2x = 2.0f * c1;

    float rb[20];
    {
        float sk_2 = 0.0f, sk_1 = s1;
        rb[0] = s1 * fc;
        #pragma unroll
        for (int k = 1; k < 20; ++k) {
            const float sk = c2x * sk_1 - sk_2;
            rb[k] = sk * fc;
            sk_2 = sk_1; sk_1 = sk;
        }
    }

    const float x2 = ux*ux, y2 = uy*uy, z2 = uz*uz;
    const float c1a = 0.4886025119029199f;
    const float c2a = 1.0925484305920792f;
    float an[16];
    an[0]  = 0.28209479177387814f;
    an[1]  = c1a * uy;
    an[2]  = c1a * uz;
    an[3]  = c1a * ux;
    an[4]  = c2a * ux * uy;
    an[5]  = c2a * uy * uz;
    an[6]  = 0.31539156525252005f * (3.0f*z2 - 1.0f);
    an[7]  = c2a * ux * uz;
    an[8]  = 0.5462742152960396f * (x2 - y2);
    an[9]  = 0.5900435899266435f * uy * (3.0f*x2 - y2);
    an[10] = 2.890611442640554f  * ux * uy * uz;
    an[11] = 0.4570457994644658f * uy * (5.0f*z2 - 1.0f);
    an[12] = 0.3731763325901154f * uz * (5.0f*z2 - 3.0f);
    an[13] = 0.4570457994644658f * ux * (5.0f*z2 - 1.0f);
    an[14] = 1.445305721320277f  * uz * (x2 - y2);
    an[15] = 0.5900435899266435f * ux * (x2 - 3.0f*y2);

    float4* row = (float4*)(feat + (size_t)e * ROW);
    row[0]  = float4{rb[0],  rb[1],  rb[2],  rb[3]};
    row[1]  = float4{rb[4],  rb[5],  rb[6],  rb[7]};
    row[2]  = float4{rb[8],  rb[9],  rb[10], rb[11]};
    row[3]  = float4{rb[12], rb[13], rb[14], rb[15]};
    row[4]  = float4{rb[16], rb[17], rb[18], rb[19]};
    // angular pairs (pidx): 0:(an0,an0) 1:(an1,an2) 2:(an3,an3) 3:(an4,an5) 4:(an6,an7)
    //                       5:(an8,an8) 6:(an9,an10) 7:(an11,an12) 8:(an13,an14) 9:(an15,an15)
    row[5]  = float4{an[0],  an[0],  an[1],  an[2]};
    row[6]  = float4{an[3],  an[3],  an[4],  an[5]};
    row[7]  = float4{an[6],  an[7],  an[8],  an[8]};
    row[8]  = float4{an[9],  an[10], an[11], an[12]};
    row[9]  = float4{an[13], an[14], an[15], an[15]};
    row[10] = spv;
}

// ---- kernel B: one wave per atom, registers only (no LDS, no barriers) ----
__global__ __launch_bounds__(256) void sph_reduce_kernel(
    const float* __restrict__ feat,
    const int*   __restrict__ starts,
    float*       __restrict__ out)
{
    const int wave = threadIdx.x >> 6;
    const int lane = threadIdx.x & 63;
    const int atom = blockIdx.x * 4 + wave;

    // tile decode: 43 active lanes, each owns 2m x 4n x 4c = 32 outputs
    int n0 = 0, m0 = 0, m1 = 0, nl = 0, pidx = 0, stride = 0; long base = 0;
    const bool active = (lane < 43);
    if (lane < 5)        { n0 = 4*lane;                                   m0 = 0; m1 = 0;                        nl = 20; pidx = 0;         base = 0;       stride = 80;  }
    else if (lane < 15)  { int q = lane-5;  int pr = q/5;  n0 = 4*(q%5);  m0 = 2*pr; m1 = (m0+1 < 3) ? m0+1 : 2; nl = 18; pidx = 1 + pr;    base = 800000;  stride = 216; }
    else if (lane < 27)  { int q = lane-15; int pr = q/4;  n0 = 4*(q%4);  m0 = 2*pr; m1 = (m0+1 < 5) ? m0+1 : 4; nl = 16; pidx = 3 + pr;    base = 2960000; stride = 320; }
    else if (lane < 43)  { int q = lane-27; int pr = q/4;  n0 = 4*(q%4);  m0 = 2*pr; m1 = (m0+1 < 7) ? m0+1 : 6; nl = 14; pidx = 6 + pr;    base = 6160000; stride = 392; }

    float4 acc[8];
    #pragma unroll
    for (int k = 0; k < 8; ++k) acc[k] = float4{0.f, 0.f, 0.f, 0.f};

    const int start = starts[atom];
    const int end   = starts[atom + 1];

    if (active) {
        #pragma unroll 4
        for (int e = start; e < end; ++e) {
            const float* f = feat + (size_t)e * ROW;
            const float4 rq = *(const float4*)(f + n0);
            const float2 ap = *(const float2*)(f + 20 + 2*pidx);
            const float4 sv = *(const float4*)(f + 40);
            const float rr[4] = {rq.x, rq.y, rq.z, rq.w};
            const float aa[2] = {ap.x, ap.y};
            #pragma unroll
            for (int mi = 0; mi < 2; ++mi) {
                #pragma unroll
                for (int ni = 0; ni < 4; ++ni) {
                    const float p = rr[ni] * aa[mi];
                    float4& A = acc[mi*4 + ni];
                    A.x += p * sv.x; A.y += p * sv.y; A.z += p * sv.z; A.w += p * sv.w;
                }
            }
        }

        float* ob = out + base + (size_t)atom * (size_t)stride;
        #pragma unroll
        for (int mi = 0; mi < 2; ++mi) {
            if (mi == 0 || m1 != m0) {
                const int m = mi ? m1 : m0;
                #pragma unroll
                for (int ni = 0; ni < 4; ++ni) {
                    const int n = n0 + ni;
                    if (n < nl) *(float4*)(ob + (size_t)(m*nl + n)*4) = acc[mi*4 + ni];
                }
            }
        }
    }
}

extern "C" void kernel_launch(void* const* d_in, const int* in_sizes, int n_in,
                              void* d_out, int out_size, void* d_ws, size_t ws_size,
                              hipStream_t stream) {
    const float* R    = (const float*)d_in[0];
    const int*   i_   = (const int*)  d_in[1];
    const int*   j_   = (const int*)  d_in[2];
    const int*   sp   = (const int*)  d_in[3];
    const float* emb  = (const float*)d_in[4];
    float* out = (float*)d_out;

    float* feat   = (float*)d_ws;                                  // 33.6 MiB
    int*   starts = (int*)((char*)d_ws + (size_t)36 * 1024 * 1024); // 40 KB

    edge_feat_kernel<<<(N_EDGES + 255) / 256, 256, 0, stream>>>(R, i_, j_, sp, emb, feat, starts);
    sph_reduce_kernel<<<N_ATOMS / 4, 256, 0, stream>>>(feat, starts, out);
}

// Round 5
// 96.658 us; speedup vs baseline: 1.2785x; 1.2785x over previous
//
#include <hip/hip_runtime.h>

#define N_ATOMS 10000
#define N_EDGES 200000
#define GA 4           // atoms per block (edges contiguous: i is sorted)
#define EB 128         // edges staged per batch
#define ROW 44         // dwords per LDS feature row (176 B)
#define W_F 0.6283185307179586f   // pi/5 in f32

// ---- kernel A: starts[a] = lower_bound(seg_i, a), parallel over atoms ----
__global__ __launch_bounds__(256) void seg_starts_kernel(
    const int* __restrict__ seg_i, int* __restrict__ starts)
{
    const int a = blockIdx.x * blockDim.x + threadIdx.x;
    if (a > N_ATOMS) return;
    int lo = 0, hi = N_EDGES;
    while (lo < hi) {
        int mid = (lo + hi) >> 1;
        if (seg_i[mid] < a) lo = mid + 1; else hi = mid;
    }
    starts[a] = lo;
}

// ---- kernel B: 4 atoms per block; block-wide Phase A staging, wave-per-atom Phase B ----
// LDS row: dw 0-19 rad, dw 20-39 angular pairs (10 float2), dw 40-43 sp.
__global__ __launch_bounds__(256) void sph_expand_kernel(
    const float* __restrict__ R,
    const int*   __restrict__ starts,
    const int*   __restrict__ idx_j,
    const int*   __restrict__ species,
    const float* __restrict__ emb,
    float*       __restrict__ out)
{
    __shared__ float feat[EB][ROW];   // 128*44*4 = 22528 B
    const int tid  = threadIdx.x;
    const int wave = tid >> 6;
    const int lane = tid & 63;
    const int atom_base = blockIdx.x * GA;
    const int atom = atom_base + wave;

    // Phase-B tile decode: 43 active lanes per wave, each 2m x 4n x 4c = 32 outputs
    int n0 = 0, m0 = 0, m1 = 0, nl = 0, pidx = 0, stride = 0; long base = 0;
    const bool active = (lane < 43);
    if (lane < 5)        { n0 = 4*lane;                                   m0 = 0; m1 = 0;                        nl = 20; pidx = 0;       base = 0;       stride = 80;  }
    else if (lane < 15)  { int q = lane-5;  int pr = q/5;  n0 = 4*(q%5);  m0 = 2*pr; m1 = (m0+1 < 3) ? m0+1 : 2; nl = 18; pidx = 1 + pr;  base = 800000;  stride = 216; }
    else if (lane < 27)  { int q = lane-15; int pr = q/4;  n0 = 4*(q%4);  m0 = 2*pr; m1 = (m0+1 < 5) ? m0+1 : 4; nl = 16; pidx = 3 + pr;  base = 2960000; stride = 320; }
    else if (lane < 43)  { int q = lane-27; int pr = q/4;  n0 = 4*(q%4);  m0 = 2*pr; m1 = (m0+1 < 7) ? m0+1 : 6; nl = 14; pidx = 6 + pr;  base = 6160000; stride = 392; }

    float4 acc[8];
    #pragma unroll
    for (int k = 0; k < 8; ++k) acc[k] = float4{0.f, 0.f, 0.f, 0.f};

    const int gstart = starts[atom_base];
    const int gend   = starts[atom_base + GA];
    const int astart = starts[atom];
    const int aend   = starts[atom + 1];

    for (int e0 = gstart; e0 < gend; e0 += EB) {
        const int cnt = min(EB, gend - e0);
        __syncthreads();   // protect LDS from previous batch's readers
        if (tid < cnt) {
            const int g = e0 + tid;
            const int jj = idx_j[g];
            const float x = R[3*g + 0];
            const float y = R[3*g + 1];
            const float z = R[3*g + 2];
            const int sidx = species[jj];
            const float r   = sqrtf(x*x + y*y + z*z);
            const float inv = 1.0f / (r + 1e-12f);
            const float ux = x*inv, uy = y*inv, uz = z*inv;
            const float4 spv = *(const float4*)&emb[4 * sidx];

            // one sin + one cos; higher harmonics via Chebyshev recurrence
            const float t1 = W_F * r;
            const float s1 = sinf(t1);
            const float c1 = cosf(t1);
            const float fc = (r < 5.0f) ? (0.5f * (c1 + 1.0f)) : 0.0f;
            const float c2x = 2.0f * c1;

            float rb[20];
            {
                float sk_2 = 0.0f, sk_1 = s1;
                rb[0] = s1 * fc;
                #pragma unroll
                for (int k = 1; k < 20; ++k) {
                    const float sk = c2x * sk_1 - sk_2;
                    rb[k] = sk * fc;
                    sk_2 = sk_1; sk_1 = sk;
                }
            }

            const float x2 = ux*ux, y2 = uy*uy, z2 = uz*uz;
            const float c1a = 0.4886025119029199f;
            const float c2a = 1.0925484305920792f;
            float an[16];
            an[0]  = 0.28209479177387814f;
            an[1]  = c1a * uy;
            an[2]  = c1a * uz;
            an[3]  = c1a * ux;
            an[4]  = c2a * ux * uy;
            an[5]  = c2a * uy * uz;
            an[6]  = 0.31539156525252005f * (3.0f*z2 - 1.0f);
            an[7]  = c2a * ux * uz;
            an[8]  = 0.5462742152960396f * (x2 - y2);
            an[9]  = 0.5900435899266435f * uy * (3.0f*x2 - y2);
            an[10] = 2.890611442640554f  * ux * uy * uz;
            an[11] = 0.4570457994644658f * uy * (5.0f*z2 - 1.0f);
            an[12] = 0.3731763325901154f * uz * (5.0f*z2 - 3.0f);
            an[13] = 0.4570457994644658f * ux * (5.0f*z2 - 1.0f);
            an[14] = 1.445305721320277f  * uz * (x2 - y2);
            an[15] = 0.5900435899266435f * ux * (x2 - 3.0f*y2);

            float4* row = (float4*)&feat[tid][0];
            row[0]  = float4{rb[0],  rb[1],  rb[2],  rb[3]};
            row[1]  = float4{rb[4],  rb[5],  rb[6],  rb[7]};
            row[2]  = float4{rb[8],  rb[9],  rb[10], rb[11]};
            row[3]  = float4{rb[12], rb[13], rb[14], rb[15]};
            row[4]  = float4{rb[16], rb[17], rb[18], rb[19]};
            // angular pairs (pidx): 0:(an0,an0) 1:(an1,an2) 2:(an3,an3) 3:(an4,an5) 4:(an6,an7)
            //                       5:(an8,an8) 6:(an9,an10) 7:(an11,an12) 8:(an13,an14) 9:(an15,an15)
            row[5]  = float4{an[0],  an[0],  an[1],  an[2]};
            row[6]  = float4{an[3],  an[3],  an[4],  an[5]};
            row[7]  = float4{an[6],  an[7],  an[8],  an[8]};
            row[8]  = float4{an[9],  an[10], an[11], an[12]};
            row[9]  = float4{an[13], an[14], an[15], an[15]};
            row[10] = spv;
        }
        __syncthreads();

        // Phase B: each wave accumulates its own atom's slice of this batch
        const int lo = max(astart, e0);
        const int hi = min(aend, e0 + cnt);
        if (active) {
            for (int e = lo; e < hi; ++e) {
                const float* f = &feat[e - e0][0];
                const float4 rq = *(const float4*)(f + n0);
                const float2 ap = *(const float2*)(f + 20 + 2*pidx);
                const float4 sv = *(const float4*)(f + 40);
                const float rr[4] = {rq.x, rq.y, rq.z, rq.w};
                const float aa[2] = {ap.x, ap.y};
                #pragma unroll
                for (int mi = 0; mi < 2; ++mi) {
                    #pragma unroll
                    for (int ni = 0; ni < 4; ++ni) {
                        const float p = rr[ni] * aa[mi];
                        float4& A = acc[mi*4 + ni];
                        A.x += p * sv.x; A.y += p * sv.y; A.z += p * sv.z; A.w += p * sv.w;
                    }
                }
            }
        }
    }

    if (active) {
        float* ob = out + base + (size_t)atom * (size_t)stride;
        #pragma unroll
        for (int mi = 0; mi < 2; ++mi) {
            if (mi == 0 || m1 != m0) {
                const int m = mi ? m1 : m0;
                #pragma unroll
                for (int ni = 0; ni < 4; ++ni) {
                    const int n = n0 + ni;
                    if (n < nl) *(float4*)(ob + (size_t)(m*nl + n)*4) = acc[mi*4 + ni];
                }
            }
        }
    }
}

extern "C" void kernel_launch(void* const* d_in, const int* in_sizes, int n_in,
                              void* d_out, int out_size, void* d_ws, size_t ws_size,
                              hipStream_t stream) {
    const float* R    = (const float*)d_in[0];
    const int*   i_   = (const int*)  d_in[1];
    const int*   j_   = (const int*)  d_in[2];
    const int*   sp   = (const int*)  d_in[3];
    const float* emb  = (const float*)d_in[4];
    float* out = (float*)d_out;
    int*   starts = (int*)d_ws;   // 10001 ints

    seg_starts_kernel<<<(N_ATOMS + 256) / 256, 256, 0, stream>>>(i_, starts);
    sph_expand_kernel<<<N_ATOMS / GA, 256, 0, stream>>>(R, starts, j_, sp, emb, out);
}

// Round 6
// 95.263 us; speedup vs baseline: 1.2972x; 1.0146x over previous
//
#include <hip/hip_runtime.h>

#define N_ATOMS 10000
#define N_EDGES 200000
#define EB 56          // edges staged per batch; LDS 56*44*4 = 9856 B -> 16 blocks/CU
#define ROW 44         // dwords per LDS feature row (176 B)
#define W_F 0.6283185307179586f   // pi/5 in f32

// One wave per atom. No __syncthreads anywhere: single-wave block, LDS ops
// complete in order within a wave (validated R3); wave_barrier only fences
// compiler reordering.
__global__ __launch_bounds__(64, 4) void sph_kernel(
    const float* __restrict__ R,
    const int*   __restrict__ seg_i,
    const int*   __restrict__ idx_j,
    const int*   __restrict__ species,
    const float* __restrict__ emb,
    float*       __restrict__ out)
{
    __shared__ float feat[EB][ROW];
    const int atom = blockIdx.x;
    const int lane = threadIdx.x;   // 0..63

    // ---- edge range [s, e) for this atom (i sorted) ----
    // windowed scalar binary search for s; run end via vector load + ballot.
    int lo = 0, hi = N_EDGES;
    {
        const int g = atom * 20;                 // statistical estimate of starts[atom]
        int wlo = g - 2048; if (wlo < 0) wlo = 0;
        int whi = g + 2048; if (whi > N_EDGES) whi = N_EDGES;
        const bool ok_lo = (wlo == 0)       || (seg_i[wlo - 1] < atom);
        const bool ok_hi = (whi == N_EDGES) || (seg_i[whi] >= atom);
        if (ok_lo && ok_hi) { lo = wlo; hi = whi; }   // else: full-range fallback
    }
    while (lo < hi) {
        int mid = (lo + hi) >> 1;
        if (seg_i[mid] < atom) lo = mid + 1; else hi = mid;
    }
    const int s = lo;
    int e = s;
    for (;;) {                                   // find first index with seg_i > atom
        const int probe = e + lane;
        const int v = (probe < N_EDGES) ? seg_i[probe] : (N_ATOMS + 1);
        const unsigned long long m = __ballot(v > atom);
        if (m) { e += __ffsll((long long)m) - 1; break; }
        e += 64;
    }

    // ---- Phase-B tile decode: 43 active lanes, each 2m x 4n x 4c = 32 outputs ----
    int n0 = 0, m0 = 0, m1 = 0, nl = 0, pidx = 0, stride = 0; long base = 0;
    const bool active = (lane < 43);
    if (lane < 5)        { n0 = 4*lane;                                   m0 = 0; m1 = 0;                        nl = 20; pidx = 0;       base = 0;       stride = 80;  }
    else if (lane < 15)  { int q = lane-5;  int pr = q/5;  n0 = 4*(q%5);  m0 = 2*pr; m1 = (m0+1 < 3) ? m0+1 : 2; nl = 18; pidx = 1 + pr;  base = 800000;  stride = 216; }
    else if (lane < 27)  { int q = lane-15; int pr = q/4;  n0 = 4*(q%4);  m0 = 2*pr; m1 = (m0+1 < 5) ? m0+1 : 4; nl = 16; pidx = 3 + pr;  base = 2960000; stride = 320; }
    else if (lane < 43)  { int q = lane-27; int pr = q/4;  n0 = 4*(q%4);  m0 = 2*pr; m1 = (m0+1 < 7) ? m0+1 : 6; nl = 14; pidx = 6 + pr;  base = 6160000; stride = 392; }

    float4 acc[8];
    #pragma unroll
    for (int k = 0; k < 8; ++k) acc[k] = float4{0.f, 0.f, 0.f, 0.f};

    for (int e0 = s; e0 < e; e0 += EB) {
        const int cnt = min(EB, e - e0);

        // ---- Phase A: lane stages edge e0+lane ----
        if (lane < cnt) {
            const int g = e0 + lane;
            const int jj = idx_j[g];
            const float x = R[3*g + 0];
            const float y = R[3*g + 1];
            const float z = R[3*g + 2];
            const int sidx = species[jj];
            const float r   = sqrtf(x*x + y*y + z*z);
            const float inv = 1.0f / (r + 1e-12f);
            const float ux = x*inv, uy = y*inv, uz = z*inv;
            const float4 spv = *(const float4*)&emb[4 * sidx];

            // one sin + one cos; higher harmonics via Chebyshev recurrence
            const float t1 = W_F * r;
            const float s1 = sinf(t1);
            const float c1 = cosf(t1);
            const float fc = (r < 5.0f) ? (0.5f * (c1 + 1.0f)) : 0.0f;
            const float c2x = 2.0f * c1;

            float rb[20];
            {
                float sk_2 = 0.0f, sk_1 = s1;
                rb[0] = s1 * fc;
                #pragma unroll
                for (int k = 1; k < 20; ++k) {
                    const float sk = c2x * sk_1 - sk_2;
                    rb[k] = sk * fc;
                    sk_2 = sk_1; sk_1 = sk;
                }
            }

            const float x2 = ux*ux, y2 = uy*uy, z2 = uz*uz;
            const float c1a = 0.4886025119029199f;
            const float c2a = 1.0925484305920792f;
            float an[16];
            an[0]  = 0.28209479177387814f;
            an[1]  = c1a * uy;
            an[2]  = c1a * uz;
            an[3]  = c1a * ux;
            an[4]  = c2a * ux * uy;
            an[5]  = c2a * uy * uz;
            an[6]  = 0.31539156525252005f * (3.0f*z2 - 1.0f);
            an[7]  = c2a * ux * uz;
            an[8]  = 0.5462742152960396f * (x2 - y2);
            an[9]  = 0.5900435899266435f * uy * (3.0f*x2 - y2);
            an[10] = 2.890611442640554f  * ux * uy * uz;
            an[11] = 0.4570457994644658f * uy * (5.0f*z2 - 1.0f);
            an[12] = 0.3731763325901154f * uz * (5.0f*z2 - 3.0f);
            an[13] = 0.4570457994644658f * ux * (5.0f*z2 - 1.0f);
            an[14] = 1.445305721320277f  * uz * (x2 - y2);
            an[15] = 0.5900435899266435f * ux * (x2 - 3.0f*y2);

            float4* row = (float4*)&feat[lane][0];
            row[0]  = float4{rb[0],  rb[1],  rb[2],  rb[3]};
            row[1]  = float4{rb[4],  rb[5],  rb[6],  rb[7]};
            row[2]  = float4{rb[8],  rb[9],  rb[10], rb[11]};
            row[3]  = float4{rb[12], rb[13], rb[14], rb[15]};
            row[4]  = float4{rb[16], rb[17], rb[18], rb[19]};
            // angular pairs (pidx): 0:(an0,an0) 1:(an1,an2) 2:(an3,an3) 3:(an4,an5) 4:(an6,an7)
            //                       5:(an8,an8) 6:(an9,an10) 7:(an11,an12) 8:(an13,an14) 9:(an15,an15)
            row[5]  = float4{an[0],  an[0],  an[1],  an[2]};
            row[6]  = float4{an[3],  an[3],  an[4],  an[5]};
            row[7]  = float4{an[6],  an[7],  an[8],  an[8]};
            row[8]  = float4{an[9],  an[10], an[11], an[12]};
            row[9]  = float4{an[13], an[14], an[15], an[15]};
            row[10] = spv;
        }
        __builtin_amdgcn_wave_barrier();   // fence compiler: writes before reads

        // ---- Phase B: 43 lanes accumulate this batch ----
        if (active) {
            const float* f = &feat[0][0];
            for (int t = 0; t < cnt; ++t, f += ROW) {
                const float4 rq = *(const float4*)(f + n0);
                const float2 ap = *(const float2*)(f + 20 + 2*pidx);
                const float4 sv = *(const float4*)(f + 40);
                const float rr[4] = {rq.x, rq.y, rq.z, rq.w};
                const float aa[2] = {ap.x, ap.y};
                #pragma unroll
                for (int mi = 0; mi < 2; ++mi) {
                    #pragma unroll
                    for (int ni = 0; ni < 4; ++ni) {
                        const float p = rr[ni] * aa[mi];
                        float4& A = acc[mi*4 + ni];
                        A.x += p * sv.x; A.y += p * sv.y; A.z += p * sv.z; A.w += p * sv.w;
                    }
                }
            }
        }
        __builtin_amdgcn_wave_barrier();   // fence: reads before next batch's writes
    }

    if (active) {   // unconditional on edge count: empty atoms must write zeros
        float* ob = out + base + (size_t)atom * (size_t)stride;
        #pragma unroll
        for (int mi = 0; mi < 2; ++mi) {
            if (mi == 0 || m1 != m0) {
                const int m = mi ? m1 : m0;
                #pragma unroll
                for (int ni = 0; ni < 4; ++ni) {
                    const int n = n0 + ni;
                    if (n < nl) *(float4*)(ob + (size_t)(m*nl + n)*4) = acc[mi*4 + ni];
                }
            }
        }
    }
}

extern "C" void kernel_launch(void* const* d_in, const int* in_sizes, int n_in,
                              void* d_out, int out_size, void* d_ws, size_t ws_size,
                              hipStream_t stream) {
    const float* R    = (const float*)d_in[0];
    const int*   i_   = (const int*)  d_in[1];
    const int*   j_   = (const int*)  d_in[2];
    const int*   sp   = (const int*)  d_in[3];
    const float* emb  = (const float*)d_in[4];
    float* out = (float*)d_out;

    sph_kernel<<<N_ATOMS, 64, 0, stream>>>(R, i_, j_, sp, emb, out);
}